// Round 5
// baseline (784.604 us; speedup 1.0000x reference)
//
#include <hip/hip_runtime.h>
#include <cstdint>
#include <cstddef>

// ---------------------------------------------------------------------------
// Transformer block (B=4, T=2048, C=1024, H=16, D=64) on gfx950.
// Round 4: attn reverted to R2 (252us, 0 conflicts). GEMMs moved to a 256x256
// BK=64 double-buffered structure: per K-tile 4 quadrant-phases interleaving
// GLL16 prefetch of tile t+1 with ds_read+MFMA of tile t; ONE vmcnt(0)+
// s_barrier per K-tile (loads get a full tile of compute cover). LDS swizzle
// = slot^=(row&7) (measured 0 conflicts in R2 attn, same read pattern).
// ---------------------------------------------------------------------------

typedef __attribute__((ext_vector_type(8))) __bf16 bf16x8;
typedef __attribute__((ext_vector_type(8))) unsigned short u16x8;
typedef __attribute__((ext_vector_type(4))) float f32x4;

static constexpr int Bn = 4;
static constexpr int Tn = 2048;
static constexpr int Cn = 1024;
static constexpr int Hn = 16;
static constexpr int Dn = 64;

__device__ __forceinline__ unsigned short f2bf(float f) {
    unsigned int u = __builtin_bit_cast(unsigned int, f);
    u += 0x7fffu + ((u >> 16) & 1u);
    return (unsigned short)(u >> 16);
}

#define GLL16(gp, lp) __builtin_amdgcn_global_load_lds( \
    (const __attribute__((address_space(1))) void*)(gp), \
    (__attribute__((address_space(3))) void*)(lp), 16, 0, 0)

// ---------------------------------------------------------------------------
// fp32 -> bf16 conversion (weights)
// ---------------------------------------------------------------------------
__global__ __launch_bounds__(256) void conv_bf16(const float* __restrict__ in,
                                                 unsigned short* __restrict__ out,
                                                 int n4) {
    int i = blockIdx.x * 256 + threadIdx.x;
    if (i < n4) {
        float4 v = ((const float4*)in)[i];
        ushort4 o;
        o.x = f2bf(v.x); o.y = f2bf(v.y); o.z = f2bf(v.z); o.w = f2bf(v.w);
        ((ushort4*)out)[i] = o;
    }
}

// ---------------------------------------------------------------------------
// LayerNorm: fp32 in [rows][1024] -> bf16 out. One block (256 thr) per row.
// ---------------------------------------------------------------------------
__global__ __launch_bounds__(256) void ln_kernel(const float* __restrict__ x,
                                                 const float* __restrict__ g,
                                                 const float* __restrict__ b,
                                                 unsigned short* __restrict__ out) {
    __shared__ float red[8];
    const int row = blockIdx.x;
    const int tid = threadIdx.x;
    const float4 v = ((const float4*)(x + (size_t)row * Cn))[tid];
    float s = v.x + v.y + v.z + v.w;
    float q = v.x * v.x + v.y * v.y + v.z * v.z + v.w * v.w;
    #pragma unroll
    for (int m = 1; m < 64; m <<= 1) {
        s += __shfl_xor(s, m, 64);
        q += __shfl_xor(q, m, 64);
    }
    const int wave = tid >> 6;
    if ((tid & 63) == 0) { red[wave] = s; red[4 + wave] = q; }
    __syncthreads();
    s = red[0] + red[1] + red[2] + red[3];
    q = red[4] + red[5] + red[6] + red[7];
    const float mu  = s * (1.0f / Cn);
    const float var = q * (1.0f / Cn) - mu * mu;
    const float rstd = rsqrtf(var + 1e-5f);
    const float4 gv = ((const float4*)g)[tid];
    const float4 bv = ((const float4*)b)[tid];
    ushort4 o;
    o.x = f2bf((v.x - mu) * rstd * gv.x + bv.x);
    o.y = f2bf((v.y - mu) * rstd * gv.y + bv.y);
    o.z = f2bf((v.z - mu) * rstd * gv.z + bv.z);
    o.w = f2bf((v.w - mu) * rstd * gv.w + bv.w);
    ((ushort4*)(out + (size_t)row * Cn))[tid] = o;
}

// ---------------------------------------------------------------------------
// GEMM 256x256, BK=64, 8 waves (2Mx4N), LDS double-buffered, swizzled.
// C[M,N] = A[M,K](bf16) @ W[N,K](bf16)^T + bias; GELU / RES epilogues.
// Per K-tile: 4 phases {2x GLL16 prefetch || 4x ds_read_b128 || 16 MFMA}.
// One vmcnt(0) + s_barrier per K-tile.
// ---------------------------------------------------------------------------
template <bool GELU, bool RES>
__global__ __launch_bounds__(512, 2)
void gemm256(const unsigned short* __restrict__ A,
             const unsigned short* __restrict__ W,
             const float* __restrict__ bias,
             const float* __restrict__ res,
             void* __restrict__ out,
             int M, int N, int K) {
    __shared__ unsigned short aL[2][256 * 64];
    __shared__ unsigned short bL[2][256 * 64];
    const int tid  = threadIdx.x;          // 0..511
    const int lane = tid & 63;
    const int wave = tid >> 6;             // 0..7
    const int wm = wave >> 2;              // 0..1  (M half: 128 rows)
    const int wn = wave & 3;               // 0..3  (N quarter: 64 cols)
    const int bm0 = blockIdx.y * 256, bn0 = blockIdx.x * 256;
    const int l15 = lane & 15, l4 = lane >> 4;
    const int NT = K >> 6;                 // K-tiles of 64

    // precomputed per-thread staging sources (swizzled global col) and dests.
    // group g: 0=A rows 0-127, 1=A rows 128-255, 2=B rows 0-127, 3=B 128-255
    // chunk within half: ch = i*512+tid -> row=ch>>3, slot=ch&7
    const unsigned short* srcA[2][2];
    const unsigned short* srcB[2][2];
    int dstc[2][2]; // dest chunk index within a 256x64 tile
    #pragma unroll
    for (int gh = 0; gh < 2; ++gh) {
        #pragma unroll
        for (int i = 0; i < 2; ++i) {
            const int ch = i * 512 + tid;
            const int row = ch >> 3, sl = ch & 7;
            const int srow = gh * 128 + row;
            const int scol = (sl ^ (srow & 7)) << 3;
            srcA[gh][i] = A + (size_t)(bm0 + srow) * K + scol;
            srcB[gh][i] = W + (size_t)(bn0 + srow) * K + scol;
            dstc[gh][i] = gh * 1024 + ch;
        }
    }

    f32x4 acc[8][4] = {};

    // prologue: stage K-tile 0 into buf 0
    #pragma unroll
    for (int gh = 0; gh < 2; ++gh)
        #pragma unroll
        for (int i = 0; i < 2; ++i) {
            GLL16(srcA[gh][i], &aL[0][dstc[gh][i] * 8]);
            GLL16(srcB[gh][i], &bL[0][dstc[gh][i] * 8]);
        }
    asm volatile("s_waitcnt vmcnt(0)" ::: "memory");
    __builtin_amdgcn_sched_barrier(0);
    __builtin_amdgcn_s_barrier();

    for (int t = 0; t < NT; ++t) {
        const int cur = t & 1, nxt = cur ^ 1;
        const bool pf = (t + 1 < NT);
        const int kt1 = (t + 1) << 6;

        // phase 0: prefetch group 0 (A half 0), read all B-frags + A-quad 0
        if (pf) {
            GLL16(srcA[0][0] + kt1, &aL[nxt][dstc[0][0] * 8]);
            GLL16(srcA[0][1] + kt1, &aL[nxt][dstc[0][1] * 8]);
        }
        bf16x8 bfr[4][2];
        #pragma unroll
        for (int ni = 0; ni < 4; ++ni)
            #pragma unroll
            for (int kk = 0; kk < 2; ++kk) {
                const int row = wn * 64 + ni * 16 + l15;
                const int sl = (kk * 4 + l4) ^ (row & 7);
                bfr[ni][kk] = *(const bf16x8*)&bL[cur][row * 64 + sl * 8];
            }

        #pragma unroll
        for (int q = 0; q < 4; ++q) {
            // prefetch groups 1..3 staggered across quadrant phases
            if (q == 1 && pf) {
                GLL16(srcA[1][0] + kt1, &aL[nxt][dstc[1][0] * 8]);
                GLL16(srcA[1][1] + kt1, &aL[nxt][dstc[1][1] * 8]);
            }
            if (q == 2 && pf) {
                GLL16(srcB[0][0] + kt1, &bL[nxt][dstc[0][0] * 8]);
                GLL16(srcB[0][1] + kt1, &bL[nxt][dstc[0][1] * 8]);
            }
            if (q == 3 && pf) {
                GLL16(srcB[1][0] + kt1, &bL[nxt][dstc[1][0] * 8]);
                GLL16(srcB[1][1] + kt1, &bL[nxt][dstc[1][1] * 8]);
            }
            bf16x8 afr[2][2];
            #pragma unroll
            for (int m2 = 0; m2 < 2; ++m2)
                #pragma unroll
                for (int kk = 0; kk < 2; ++kk) {
                    const int row = wm * 128 + (q * 2 + m2) * 16 + l15;
                    const int sl = (kk * 4 + l4) ^ (row & 7);
                    afr[m2][kk] = *(const bf16x8*)&aL[cur][row * 64 + sl * 8];
                }
            __builtin_amdgcn_s_setprio(1);
            #pragma unroll
            for (int m2 = 0; m2 < 2; ++m2)
                #pragma unroll
                for (int ni = 0; ni < 4; ++ni)
                    #pragma unroll
                    for (int kk = 0; kk < 2; ++kk)
                        acc[q * 2 + m2][ni] = __builtin_amdgcn_mfma_f32_16x16x32_bf16(
                            afr[m2][kk], bfr[ni][kk], acc[q * 2 + m2][ni], 0, 0, 0);
            __builtin_amdgcn_s_setprio(0);
        }

        asm volatile("s_waitcnt vmcnt(0)" ::: "memory");
        __builtin_amdgcn_sched_barrier(0);
        __builtin_amdgcn_s_barrier();
    }

    // epilogue
    #pragma unroll
    for (int mi = 0; mi < 8; ++mi) {
        #pragma unroll
        for (int ni = 0; ni < 4; ++ni) {
            const int col = bn0 + wn * 64 + ni * 16 + l15;
            const float bvl = bias[col];
            #pragma unroll
            for (int j = 0; j < 4; ++j) {
                const int r = bm0 + wm * 128 + mi * 16 + l4 * 4 + j;
                float v = acc[mi][ni][j] + bvl;
                if (GELU) v = 0.5f * v * (1.0f + erff(v * 0.70710678118f));
                const size_t idx = (size_t)r * N + col;
                if (RES) ((float*)out)[idx] = res[idx] + v;
                else     ((unsigned short*)out)[idx] = f2bf(v);
            }
        }
    }
}

// ---------------------------------------------------------------------------
// Flash attention (non-causal) — R2 version (measured 252us, 0 conflicts).
// ---------------------------------------------------------------------------
__global__ __launch_bounds__(256, 2)
void attn_kernel(const unsigned short* __restrict__ qkv,
                 unsigned short* __restrict__ y) {
    __shared__ unsigned short kL[128 * 64];   // [key][d] swizzled
    __shared__ unsigned short vT[64 * 128];   // [d][key] swizzled
    __shared__ unsigned short pL[4][16 * 128];// per-wave P [qrow][key] swizzled
    const int tid  = threadIdx.x;
    const int lane = tid & 63;
    const int wave = tid >> 6;
    const int l15 = lane & 15, l4 = lane >> 4;
    const int bh = blockIdx.y, b = bh >> 4, h = bh & 15;
    const int q0 = blockIdx.x * 64;
    const size_t base = (size_t)b * Tn * (3 * Cn);

    // Q fragments in registers
    const int tq = q0 + wave * 16 + l15;
    const unsigned short* qp = qkv + base + (size_t)tq * (3 * Cn) + h * Dn;
    const bf16x8 qf0 = *(const bf16x8*)(qp + l4 * 8);
    const bf16x8 qf1 = *(const bf16x8*)(qp + 32 + l4 * 8);

    float mr[4], lr[4];
    f32x4 o[4] = {};
    #pragma unroll
    for (int j = 0; j < 4; ++j) { mr[j] = -1e30f; lr[j] = 0.0f; }

    for (int kt = 0; kt < Tn; kt += 128) {
        // stage K tile: LDS linear dest, swizzled GLOBAL source.
        #pragma unroll
        for (int i = 0; i < 4; ++i) {
            const int ch = i * 256 + tid;       // 0..1023 (16B chunks)
            const int key = ch >> 3, cs = ch & 7;
            const int c_log = cs ^ (key & 7);
            GLL16(qkv + base + (size_t)(kt + key) * (3 * Cn) + Cn + h * Dn + c_log * 8,
                  &kL[ch * 8]);
        }
        // stage V transposed: per wave one d-value x 64 consecutive keys
        #pragma unroll
        for (int i = 0; i < 4; ++i) {
            const int ch = i * 256 + tid;
            const int key = ch & 127, c = ch >> 7;   // c in 0..7
            const u16x8 vv = *(const u16x8*)(qkv + base + (size_t)(kt + key) * (3 * Cn)
                                             + 2 * Cn + h * Dn + c * 8);
            #pragma unroll
            for (int j = 0; j < 8; ++j) {
                const int d = c * 8 + j;
                const int ps = ((key >> 3) ^ (d & 15)) * 8 + (key & 7);
                vT[d * 128 + ps] = vv[j];
            }
        }
        __syncthreads();

        // S = (Q K^T) * scale for this wave's 16 q-rows x 128 keys
        f32x4 s[8];
        __builtin_amdgcn_s_setprio(1);
        #pragma unroll
        for (int ni = 0; ni < 8; ++ni) {
            const int krow = ni * 16 + l15;
            const int ks = (krow & 7) << 3;          // elem-granular swizzle
            const bf16x8 kb0 = *(const bf16x8*)&kL[krow * 64 + ((l4 * 8) ^ ks)];
            const bf16x8 kb1 = *(const bf16x8*)&kL[krow * 64 + ((32 + l4 * 8) ^ ks)];
            f32x4 a = {};
            a = __builtin_amdgcn_mfma_f32_16x16x32_bf16(qf0, kb0, a, 0, 0, 0);
            a = __builtin_amdgcn_mfma_f32_16x16x32_bf16(qf1, kb1, a, 0, 0, 0);
            s[ni] = a * 0.125f;
        }
        __builtin_amdgcn_s_setprio(0);

        // online softmax per row (rows live in 16-lane groups)
        #pragma unroll
        for (int j = 0; j < 4; ++j) {
            float tm = -1e30f;
            #pragma unroll
            for (int ni = 0; ni < 8; ++ni) tm = fmaxf(tm, s[ni][j]);
            #pragma unroll
            for (int m = 1; m < 16; m <<= 1) tm = fmaxf(tm, __shfl_xor(tm, m, 64));
            const float mn = fmaxf(mr[j], tm);
            const float al = __expf(mr[j] - mn);
            mr[j] = mn;
            float rs = 0.0f;
            #pragma unroll
            for (int ni = 0; ni < 8; ++ni) {
                const float p = __expf(s[ni][j] - mn);
                s[ni][j] = p;
                rs += p;
            }
            #pragma unroll
            for (int m = 1; m < 16; m <<= 1) rs += __shfl_xor(rs, m, 64);
            lr[j] = lr[j] * al + rs;
            #pragma unroll
            for (int di = 0; di < 4; ++di) o[di][j] *= al;
            const int row = l4 * 4 + j;
            #pragma unroll
            for (int ni = 0; ni < 8; ++ni) {
                const int col = ni * 16 + l15;
                const int ps = (((col >> 3) ^ row) << 3) | (col & 7);
                pL[wave][row * 128 + ps] = f2bf(s[ni][j]);
            }
        }

        // O += P V
        __builtin_amdgcn_s_setprio(1);
        #pragma unroll
        for (int kk = 0; kk < 4; ++kk) {
            const int pslot = (kk * 4 + l4) ^ l15;   // q-row = l15
            const bf16x8 pa = *(const bf16x8*)&pL[wave][l15 * 128 + pslot * 8];
            #pragma unroll
            for (int di = 0; di < 4; ++di) {
                const int drow = di * 16 + l15;
                const int vslot = (kk * 4 + l4) ^ (drow & 15);
                const bf16x8 vb = *(const bf16x8*)&vT[drow * 128 + vslot * 8];
                o[di] = __builtin_amdgcn_mfma_f32_16x16x32_bf16(pa, vb, o[di], 0, 0, 0);
            }
        }
        __builtin_amdgcn_s_setprio(0);
        __syncthreads();
    }

    // epilogue: y[b][t][h*64+d] = o / l
    #pragma unroll
    for (int di = 0; di < 4; ++di) {
        #pragma unroll
        for (int j = 0; j < 4; ++j) {
            const int t = q0 + wave * 16 + l4 * 4 + j;
            y[(size_t)(b * Tn + t) * Cn + h * Dn + di * 16 + l15] = f2bf(o[di][j] / lr[j]);
        }
    }
}

// ---------------------------------------------------------------------------
extern "C" void kernel_launch(void* const* d_in, const int* in_sizes, int n_in,
                              void* d_out, int out_size, void* d_ws, size_t ws_size,
                              hipStream_t stream) {
    (void)in_sizes; (void)n_in; (void)out_size; (void)ws_size;
    const float* x      = (const float*)d_in[0];
    const float* ln1_g  = (const float*)d_in[1];
    const float* ln1_b  = (const float*)d_in[2];
    const float* ln2_g  = (const float*)d_in[3];
    const float* ln2_b  = (const float*)d_in[4];
    const float* qkv_w  = (const float*)d_in[5];
    const float* qkv_b  = (const float*)d_in[6];
    const float* proj_w = (const float*)d_in[7];
    const float* proj_b = (const float*)d_in[8];
    const float* fc1_w  = (const float*)d_in[9];
    const float* fc1_b  = (const float*)d_in[10];
    const float* fc2_w  = (const float*)d_in[11];
    const float* fc2_b  = (const float*)d_in[12];

    char* ws = (char*)d_ws;
    unsigned short* wq  = (unsigned short*)(ws + 0);          //  0..6 MB
    unsigned short* wp  = (unsigned short*)(ws + 6291456);    //  6..8 MB
    unsigned short* wf1 = (unsigned short*)(ws + 8388608);    //  8..16 MB
    unsigned short* wf2 = (unsigned short*)(ws + 16777216);   // 16..24 MB
    unsigned short* h   = (unsigned short*)(ws + 25165824);   // 24..40 MB
    unsigned short* qkv = (unsigned short*)(ws + 41943040);   // 40..88 MB
    unsigned short* yb  = (unsigned short*)(ws + 92274688);   // 88..104 MB
    unsigned short* act = (unsigned short*)(ws + 41943040);   // 40..104 MB (over qkv+yb)
    float*          x2  = (float*)d_out;                      // residual stream lives in d_out

    const int BT = Bn * Tn; // 8192

    // weights -> bf16
    conv_bf16<<<dim3(3072), dim3(256), 0, stream>>>(qkv_w, wq, 3 * Cn * Cn / 4);
    conv_bf16<<<dim3(1024), dim3(256), 0, stream>>>(proj_w, wp, Cn * Cn / 4);
    conv_bf16<<<dim3(4096), dim3(256), 0, stream>>>(fc1_w, wf1, 4 * Cn * Cn / 4);
    conv_bf16<<<dim3(4096), dim3(256), 0, stream>>>(fc2_w, wf2, 4 * Cn * Cn / 4);

    // LN1
    ln_kernel<<<dim3(BT), dim3(256), 0, stream>>>(x, ln1_g, ln1_b, h);
    // QKV: [8192 x 3072 x 1024]
    gemm256<false, false><<<dim3(3 * Cn / 256, BT / 256), dim3(512), 0, stream>>>(
        h, wq, qkv_b, nullptr, qkv, BT, 3 * Cn, Cn);
    // attention
    attn_kernel<<<dim3(Tn / 64, Bn * Hn), dim3(256), 0, stream>>>(qkv, yb);
    // proj + residual -> x2 (fp32, in d_out): [8192 x 1024 x 1024]
    gemm256<false, true><<<dim3(Cn / 256, BT / 256), dim3(512), 0, stream>>>(
        yb, wp, proj_b, x, x2, BT, Cn, Cn);
    // LN2
    ln_kernel<<<dim3(BT), dim3(256), 0, stream>>>(x2, ln2_g, ln2_b, h);
    // fc1 + gelu: [8192 x 4096 x 1024]
    gemm256<true, false><<<dim3(4 * Cn / 256, BT / 256), dim3(512), 0, stream>>>(
        h, wf1, fc1_b, nullptr, act, BT, 4 * Cn, Cn);
    // fc2 + residual -> out (fp32): [8192 x 1024 x 4096]
    gemm256<false, true><<<dim3(Cn / 256, BT / 256), dim3(512), 0, stream>>>(
        act, wf2, fc2_b, x2, (float*)d_out, BT, Cn, 4 * Cn);
}

// Round 6
// 653.682 us; speedup vs baseline: 1.2003x; 1.2003x over previous
//
#include <hip/hip_runtime.h>
#include <cstdint>
#include <cstddef>

// ---------------------------------------------------------------------------
// Transformer block (B=4, T=2048, C=1024, H=16, D=64) on gfx950.
// Round 5: GEMM = minimum 2-phase recipe at 128x128, BK=64, double-buffered
// LDS (64KB -> 2 blocks/CU), staging issued at loop top, single
// __syncthreads per K-tile. No inline asm, no setprio (m190). Attn = R2
// version (measured 252us, 0 conflicts).
// ---------------------------------------------------------------------------

typedef __attribute__((ext_vector_type(8))) __bf16 bf16x8;
typedef __attribute__((ext_vector_type(8))) unsigned short u16x8;
typedef __attribute__((ext_vector_type(4))) float f32x4;

static constexpr int Bn = 4;
static constexpr int Tn = 2048;
static constexpr int Cn = 1024;
static constexpr int Hn = 16;
static constexpr int Dn = 64;

__device__ __forceinline__ unsigned short f2bf(float f) {
    unsigned int u = __builtin_bit_cast(unsigned int, f);
    u += 0x7fffu + ((u >> 16) & 1u);
    return (unsigned short)(u >> 16);
}

#define GLL16(gp, lp) __builtin_amdgcn_global_load_lds( \
    (const __attribute__((address_space(1))) void*)(gp), \
    (__attribute__((address_space(3))) void*)(lp), 16, 0, 0)

// ---------------------------------------------------------------------------
// fp32 -> bf16 conversion (weights)
// ---------------------------------------------------------------------------
__global__ __launch_bounds__(256) void conv_bf16(const float* __restrict__ in,
                                                 unsigned short* __restrict__ out,
                                                 int n4) {
    int i = blockIdx.x * 256 + threadIdx.x;
    if (i < n4) {
        float4 v = ((const float4*)in)[i];
        ushort4 o;
        o.x = f2bf(v.x); o.y = f2bf(v.y); o.z = f2bf(v.z); o.w = f2bf(v.w);
        ((ushort4*)out)[i] = o;
    }
}

// ---------------------------------------------------------------------------
// LayerNorm: fp32 in [rows][1024] -> bf16 out. One block (256 thr) per row.
// ---------------------------------------------------------------------------
__global__ __launch_bounds__(256) void ln_kernel(const float* __restrict__ x,
                                                 const float* __restrict__ g,
                                                 const float* __restrict__ b,
                                                 unsigned short* __restrict__ out) {
    __shared__ float red[8];
    const int row = blockIdx.x;
    const int tid = threadIdx.x;
    const float4 v = ((const float4*)(x + (size_t)row * Cn))[tid];
    float s = v.x + v.y + v.z + v.w;
    float q = v.x * v.x + v.y * v.y + v.z * v.z + v.w * v.w;
    #pragma unroll
    for (int m = 1; m < 64; m <<= 1) {
        s += __shfl_xor(s, m, 64);
        q += __shfl_xor(q, m, 64);
    }
    const int wave = tid >> 6;
    if ((tid & 63) == 0) { red[wave] = s; red[4 + wave] = q; }
    __syncthreads();
    s = red[0] + red[1] + red[2] + red[3];
    q = red[4] + red[5] + red[6] + red[7];
    const float mu  = s * (1.0f / Cn);
    const float var = q * (1.0f / Cn) - mu * mu;
    const float rstd = rsqrtf(var + 1e-5f);
    const float4 gv = ((const float4*)g)[tid];
    const float4 bv = ((const float4*)b)[tid];
    ushort4 o;
    o.x = f2bf((v.x - mu) * rstd * gv.x + bv.x);
    o.y = f2bf((v.y - mu) * rstd * gv.y + bv.y);
    o.z = f2bf((v.z - mu) * rstd * gv.z + bv.z);
    o.w = f2bf((v.w - mu) * rstd * gv.w + bv.w);
    ((ushort4*)(out + (size_t)row * Cn))[tid] = o;
}

// ---------------------------------------------------------------------------
// GEMM 128x128, BK=64, double-buffered LDS, 2-phase recipe:
//   iter t: STAGE(buf^1, t+1) issued first; ds_read + 32 MFMA from buf;
//           __syncthreads (vmcnt(0)+lgkmcnt(0)+s_barrier); flip.
// LDS slot-swizzle: slot ^= row&7 (16B granularity; 0 conflicts per R2).
// C[M,N] = A[M,K](bf16) @ W[N,K](bf16)^T + bias; GELU / RES epilogues.
// ---------------------------------------------------------------------------
template <bool GELU, bool RES>
__global__ __launch_bounds__(256, 2)
void gemm_bt(const unsigned short* __restrict__ A,
             const unsigned short* __restrict__ W,
             const float* __restrict__ bias,
             const float* __restrict__ res,
             void* __restrict__ out,
             int M, int N, int K) {
    __shared__ unsigned short aL[2][128 * 64];
    __shared__ unsigned short bL[2][128 * 64];
    const int tid  = threadIdx.x;
    const int lane = tid & 63;
    const int wave = tid >> 6;
    const int wm = wave >> 1, wn = wave & 1;
    const int bm0 = blockIdx.y * 128, bn0 = blockIdx.x * 128;
    const int l15 = lane & 15, l4 = lane >> 4;
    const int NT = K >> 6;

    // staging addresses: chunk ch = i*256+tid -> row=ch>>3, slot=ch&7.
    // source col pre-swizzled so LDS dest stays linear (rule #21).
    const unsigned short* srcA[4];
    const unsigned short* srcB[4];
    #pragma unroll
    for (int i = 0; i < 4; ++i) {
        const int ch = i * 256 + tid;
        const int row = ch >> 3, sl = ch & 7;
        const int scol = (sl ^ (row & 7)) << 3;
        srcA[i] = A + (size_t)(bm0 + row) * K + scol;
        srcB[i] = W + (size_t)(bn0 + row) * K + scol;
    }

    f32x4 acc[4][4] = {};

    // prologue: stage tile 0 into buf 0
    #pragma unroll
    for (int i = 0; i < 4; ++i) {
        const int ch = i * 256 + tid;
        GLL16(srcA[i], &aL[0][ch * 8]);
        GLL16(srcB[i], &bL[0][ch * 8]);
    }
    __syncthreads();

    for (int t = 0; t < NT; ++t) {
        const int cur = t & 1, nxt = cur ^ 1;
        // [1] issue next-tile staging FIRST (max latency cover)
        if (t + 1 < NT) {
            const int kt1 = (t + 1) << 6;
            #pragma unroll
            for (int i = 0; i < 4; ++i) {
                const int ch = i * 256 + tid;
                GLL16(srcA[i] + kt1, &aL[nxt][ch * 8]);
                GLL16(srcB[i] + kt1, &bL[nxt][ch * 8]);
            }
        }
        // [2] ds_read fragments (slot = (kk*4+l4) ^ (row&7))
        bf16x8 av[4][2], bv[4][2];
        #pragma unroll
        for (int ni = 0; ni < 4; ++ni)
            #pragma unroll
            for (int kk = 0; kk < 2; ++kk) {
                const int row = wn * 64 + ni * 16 + l15;
                const int sl = (kk * 4 + l4) ^ (row & 7);
                bv[ni][kk] = *(const bf16x8*)&bL[cur][row * 64 + sl * 8];
            }
        #pragma unroll
        for (int mi = 0; mi < 4; ++mi)
            #pragma unroll
            for (int kk = 0; kk < 2; ++kk) {
                const int row = wm * 64 + mi * 16 + l15;
                const int sl = (kk * 4 + l4) ^ (row & 7);
                av[mi][kk] = *(const bf16x8*)&aL[cur][row * 64 + sl * 8];
            }
        // [3] 32 MFMA
        #pragma unroll
        for (int mi = 0; mi < 4; ++mi)
            #pragma unroll
            for (int ni = 0; ni < 4; ++ni)
                #pragma unroll
                for (int kk = 0; kk < 2; ++kk)
                    acc[mi][ni] = __builtin_amdgcn_mfma_f32_16x16x32_bf16(
                        av[mi][kk], bv[ni][kk], acc[mi][ni], 0, 0, 0);
        // [4] drain staging + barrier (vmcnt(0) lgkmcnt(0) s_barrier)
        __syncthreads();
    }

    #pragma unroll
    for (int mi = 0; mi < 4; ++mi) {
        #pragma unroll
        for (int ni = 0; ni < 4; ++ni) {
            const int col = bn0 + wn * 64 + ni * 16 + l15;
            const float bvl = bias[col];
            #pragma unroll
            for (int j = 0; j < 4; ++j) {
                const int r = bm0 + wm * 64 + mi * 16 + l4 * 4 + j;
                float v = acc[mi][ni][j] + bvl;
                if (GELU) v = 0.5f * v * (1.0f + erff(v * 0.70710678118f));
                const size_t idx = (size_t)r * N + col;
                if (RES) ((float*)out)[idx] = res[idx] + v;
                else     ((unsigned short*)out)[idx] = f2bf(v);
            }
        }
    }
}

// ---------------------------------------------------------------------------
// Flash attention (non-causal) — R2 version (measured 252us, 0 conflicts).
// ---------------------------------------------------------------------------
__global__ __launch_bounds__(256, 2)
void attn_kernel(const unsigned short* __restrict__ qkv,
                 unsigned short* __restrict__ y) {
    __shared__ unsigned short kL[128 * 64];   // [key][d] swizzled
    __shared__ unsigned short vT[64 * 128];   // [d][key] swizzled
    __shared__ unsigned short pL[4][16 * 128];// per-wave P [qrow][key] swizzled
    const int tid  = threadIdx.x;
    const int lane = tid & 63;
    const int wave = tid >> 6;
    const int l15 = lane & 15, l4 = lane >> 4;
    const int bh = blockIdx.y, b = bh >> 4, h = bh & 15;
    const int q0 = blockIdx.x * 64;
    const size_t base = (size_t)b * Tn * (3 * Cn);

    const int tq = q0 + wave * 16 + l15;
    const unsigned short* qp = qkv + base + (size_t)tq * (3 * Cn) + h * Dn;
    const bf16x8 qf0 = *(const bf16x8*)(qp + l4 * 8);
    const bf16x8 qf1 = *(const bf16x8*)(qp + 32 + l4 * 8);

    float mr[4], lr[4];
    f32x4 o[4] = {};
    #pragma unroll
    for (int j = 0; j < 4; ++j) { mr[j] = -1e30f; lr[j] = 0.0f; }

    for (int kt = 0; kt < Tn; kt += 128) {
        #pragma unroll
        for (int i = 0; i < 4; ++i) {
            const int ch = i * 256 + tid;       // 0..1023 (16B chunks)
            const int key = ch >> 3, cs = ch & 7;
            const int c_log = cs ^ (key & 7);
            GLL16(qkv + base + (size_t)(kt + key) * (3 * Cn) + Cn + h * Dn + c_log * 8,
                  &kL[ch * 8]);
        }
        #pragma unroll
        for (int i = 0; i < 4; ++i) {
            const int ch = i * 256 + tid;
            const int key = ch & 127, c = ch >> 7;   // c in 0..7
            const u16x8 vv = *(const u16x8*)(qkv + base + (size_t)(kt + key) * (3 * Cn)
                                             + 2 * Cn + h * Dn + c * 8);
            #pragma unroll
            for (int j = 0; j < 8; ++j) {
                const int d = c * 8 + j;
                const int ps = ((key >> 3) ^ (d & 15)) * 8 + (key & 7);
                vT[d * 128 + ps] = vv[j];
            }
        }
        __syncthreads();

        f32x4 s[8];
        __builtin_amdgcn_s_setprio(1);
        #pragma unroll
        for (int ni = 0; ni < 8; ++ni) {
            const int krow = ni * 16 + l15;
            const int ks = (krow & 7) << 3;
            const bf16x8 kb0 = *(const bf16x8*)&kL[krow * 64 + ((l4 * 8) ^ ks)];
            const bf16x8 kb1 = *(const bf16x8*)&kL[krow * 64 + ((32 + l4 * 8) ^ ks)];
            f32x4 a = {};
            a = __builtin_amdgcn_mfma_f32_16x16x32_bf16(qf0, kb0, a, 0, 0, 0);
            a = __builtin_amdgcn_mfma_f32_16x16x32_bf16(qf1, kb1, a, 0, 0, 0);
            s[ni] = a * 0.125f;
        }
        __builtin_amdgcn_s_setprio(0);

        #pragma unroll
        for (int j = 0; j < 4; ++j) {
            float tm = -1e30f;
            #pragma unroll
            for (int ni = 0; ni < 8; ++ni) tm = fmaxf(tm, s[ni][j]);
            #pragma unroll
            for (int m = 1; m < 16; m <<= 1) tm = fmaxf(tm, __shfl_xor(tm, m, 64));
            const float mn = fmaxf(mr[j], tm);
            const float al = __expf(mr[j] - mn);
            mr[j] = mn;
            float rs = 0.0f;
            #pragma unroll
            for (int ni = 0; ni < 8; ++ni) {
                const float p = __expf(s[ni][j] - mn);
                s[ni][j] = p;
                rs += p;
            }
            #pragma unroll
            for (int m = 1; m < 16; m <<= 1) rs += __shfl_xor(rs, m, 64);
            lr[j] = lr[j] * al + rs;
            #pragma unroll
            for (int di = 0; di < 4; ++di) o[di][j] *= al;
            const int row = l4 * 4 + j;
            #pragma unroll
            for (int ni = 0; ni < 8; ++ni) {
                const int col = ni * 16 + l15;
                const int ps = (((col >> 3) ^ row) << 3) | (col & 7);
                pL[wave][row * 128 + ps] = f2bf(s[ni][j]);
            }
        }

        __builtin_amdgcn_s_setprio(1);
        #pragma unroll
        for (int kk = 0; kk < 4; ++kk) {
            const int pslot = (kk * 4 + l4) ^ l15;
            const bf16x8 pa = *(const bf16x8*)&pL[wave][l15 * 128 + pslot * 8];
            #pragma unroll
            for (int di = 0; di < 4; ++di) {
                const int drow = di * 16 + l15;
                const int vslot = (kk * 4 + l4) ^ (drow & 15);
                const bf16x8 vb = *(const bf16x8*)&vT[drow * 128 + vslot * 8];
                o[di] = __builtin_amdgcn_mfma_f32_16x16x32_bf16(pa, vb, o[di], 0, 0, 0);
            }
        }
        __builtin_amdgcn_s_setprio(0);
        __syncthreads();
    }

    #pragma unroll
    for (int di = 0; di < 4; ++di) {
        #pragma unroll
        for (int j = 0; j < 4; ++j) {
            const int t = q0 + wave * 16 + l4 * 4 + j;
            y[(size_t)(b * Tn + t) * Cn + h * Dn + di * 16 + l15] = f2bf(o[di][j] / lr[j]);
        }
    }
}

// ---------------------------------------------------------------------------
extern "C" void kernel_launch(void* const* d_in, const int* in_sizes, int n_in,
                              void* d_out, int out_size, void* d_ws, size_t ws_size,
                              hipStream_t stream) {
    (void)in_sizes; (void)n_in; (void)out_size; (void)ws_size;
    const float* x      = (const float*)d_in[0];
    const float* ln1_g  = (const float*)d_in[1];
    const float* ln1_b  = (const float*)d_in[2];
    const float* ln2_g  = (const float*)d_in[3];
    const float* ln2_b  = (const float*)d_in[4];
    const float* qkv_w  = (const float*)d_in[5];
    const float* qkv_b  = (const float*)d_in[6];
    const float* proj_w = (const float*)d_in[7];
    const float* proj_b = (const float*)d_in[8];
    const float* fc1_w  = (const float*)d_in[9];
    const float* fc1_b  = (const float*)d_in[10];
    const float* fc2_w  = (const float*)d_in[11];
    const float* fc2_b  = (const float*)d_in[12];

    char* ws = (char*)d_ws;
    unsigned short* wq  = (unsigned short*)(ws + 0);          //  0..6 MB
    unsigned short* wp  = (unsigned short*)(ws + 6291456);    //  6..8 MB
    unsigned short* wf1 = (unsigned short*)(ws + 8388608);    //  8..16 MB
    unsigned short* wf2 = (unsigned short*)(ws + 16777216);   // 16..24 MB
    unsigned short* h   = (unsigned short*)(ws + 25165824);   // 24..40 MB
    unsigned short* qkv = (unsigned short*)(ws + 41943040);   // 40..88 MB
    unsigned short* yb  = (unsigned short*)(ws + 92274688);   // 88..104 MB
    unsigned short* act = (unsigned short*)(ws + 41943040);   // 40..104 MB (over qkv+yb)
    float*          x2  = (float*)d_out;                      // residual stream in d_out

    const int BT = Bn * Tn; // 8192

    conv_bf16<<<dim3(3072), dim3(256), 0, stream>>>(qkv_w, wq, 3 * Cn * Cn / 4);
    conv_bf16<<<dim3(1024), dim3(256), 0, stream>>>(proj_w, wp, Cn * Cn / 4);
    conv_bf16<<<dim3(4096), dim3(256), 0, stream>>>(fc1_w, wf1, 4 * Cn * Cn / 4);
    conv_bf16<<<dim3(4096), dim3(256), 0, stream>>>(fc2_w, wf2, 4 * Cn * Cn / 4);

    ln_kernel<<<dim3(BT), dim3(256), 0, stream>>>(x, ln1_g, ln1_b, h);
    gemm_bt<false, false><<<dim3(3 * Cn / 128, BT / 128), dim3(256), 0, stream>>>(
        h, wq, qkv_b, nullptr, qkv, BT, 3 * Cn, Cn);
    attn_kernel<<<dim3(Tn / 64, Bn * Hn), dim3(256), 0, stream>>>(qkv, yb);
    gemm_bt<false, true><<<dim3(Cn / 128, BT / 128), dim3(256), 0, stream>>>(
        yb, wp, proj_b, x, x2, BT, Cn, Cn);
    ln_kernel<<<dim3(BT), dim3(256), 0, stream>>>(x2, ln2_g, ln2_b, h);
    gemm_bt<true, false><<<dim3(4 * Cn / 128, BT / 128), dim3(256), 0, stream>>>(
        h, wf1, fc1_b, nullptr, act, BT, 4 * Cn, Cn);
    gemm_bt<false, true><<<dim3(Cn / 128, BT / 128), dim3(256), 0, stream>>>(
        act, wf2, fc2_b, x2, (float*)d_out, BT, Cn, 4 * Cn);
}

// Round 8
// 639.934 us; speedup vs baseline: 1.2261x; 1.0215x over previous
//
#include <hip/hip_runtime.h>
#include <cstdint>
#include <cstddef>

// ---------------------------------------------------------------------------
// Transformer block (B=4, T=2048, C=1024, H=16, D=64) on gfx950.
// Round 7 = Round 6 resubmitted (acquisition timeout, no signal):
// attn KVBLK 128->64: LDS 48KB->24KB/block -> occupancy 2->5 blocks/CU
// (TLP covers the serial per-tile chain). Swizzle masks re-derived for
// 8-slot rows. GEMM/LN/conv frozen from R5 (654us best).
// ---------------------------------------------------------------------------

typedef __attribute__((ext_vector_type(8))) __bf16 bf16x8;
typedef __attribute__((ext_vector_type(8))) unsigned short u16x8;
typedef __attribute__((ext_vector_type(4))) float f32x4;

static constexpr int Bn = 4;
static constexpr int Tn = 2048;
static constexpr int Cn = 1024;
static constexpr int Hn = 16;
static constexpr int Dn = 64;

__device__ __forceinline__ unsigned short f2bf(float f) {
    unsigned int u = __builtin_bit_cast(unsigned int, f);
    u += 0x7fffu + ((u >> 16) & 1u);
    return (unsigned short)(u >> 16);
}

#define GLL16(gp, lp) __builtin_amdgcn_global_load_lds( \
    (const __attribute__((address_space(1))) void*)(gp), \
    (__attribute__((address_space(3))) void*)(lp), 16, 0, 0)

// ---------------------------------------------------------------------------
// fp32 -> bf16 conversion (weights)
// ---------------------------------------------------------------------------
__global__ __launch_bounds__(256) void conv_bf16(const float* __restrict__ in,
                                                 unsigned short* __restrict__ out,
                                                 int n4) {
    int i = blockIdx.x * 256 + threadIdx.x;
    if (i < n4) {
        float4 v = ((const float4*)in)[i];
        ushort4 o;
        o.x = f2bf(v.x); o.y = f2bf(v.y); o.z = f2bf(v.z); o.w = f2bf(v.w);
        ((ushort4*)out)[i] = o;
    }
}

// ---------------------------------------------------------------------------
// LayerNorm: fp32 in [rows][1024] -> bf16 out. One block (256 thr) per row.
// ---------------------------------------------------------------------------
__global__ __launch_bounds__(256) void ln_kernel(const float* __restrict__ x,
                                                 const float* __restrict__ g,
                                                 const float* __restrict__ b,
                                                 unsigned short* __restrict__ out) {
    __shared__ float red[8];
    const int row = blockIdx.x;
    const int tid = threadIdx.x;
    const float4 v = ((const float4*)(x + (size_t)row * Cn))[tid];
    float s = v.x + v.y + v.z + v.w;
    float q = v.x * v.x + v.y * v.y + v.z * v.z + v.w * v.w;
    #pragma unroll
    for (int m = 1; m < 64; m <<= 1) {
        s += __shfl_xor(s, m, 64);
        q += __shfl_xor(q, m, 64);
    }
    const int wave = tid >> 6;
    if ((tid & 63) == 0) { red[wave] = s; red[4 + wave] = q; }
    __syncthreads();
    s = red[0] + red[1] + red[2] + red[3];
    q = red[4] + red[5] + red[6] + red[7];
    const float mu  = s * (1.0f / Cn);
    const float var = q * (1.0f / Cn) - mu * mu;
    const float rstd = rsqrtf(var + 1e-5f);
    const float4 gv = ((const float4*)g)[tid];
    const float4 bv = ((const float4*)b)[tid];
    ushort4 o;
    o.x = f2bf((v.x - mu) * rstd * gv.x + bv.x);
    o.y = f2bf((v.y - mu) * rstd * gv.y + bv.y);
    o.z = f2bf((v.z - mu) * rstd * gv.z + bv.z);
    o.w = f2bf((v.w - mu) * rstd * gv.w + bv.w);
    ((ushort4*)(out + (size_t)row * Cn))[tid] = o;
}

// ---------------------------------------------------------------------------
// GEMM 128x128, BK=64, double-buffered LDS, 2-phase recipe (R5, frozen).
// ---------------------------------------------------------------------------
template <bool GELU, bool RES>
__global__ __launch_bounds__(256, 2)
void gemm_bt(const unsigned short* __restrict__ A,
             const unsigned short* __restrict__ W,
             const float* __restrict__ bias,
             const float* __restrict__ res,
             void* __restrict__ out,
             int M, int N, int K) {
    __shared__ unsigned short aL[2][128 * 64];
    __shared__ unsigned short bL[2][128 * 64];
    const int tid  = threadIdx.x;
    const int lane = tid & 63;
    const int wave = tid >> 6;
    const int wm = wave >> 1, wn = wave & 1;
    const int bm0 = blockIdx.y * 128, bn0 = blockIdx.x * 128;
    const int l15 = lane & 15, l4 = lane >> 4;
    const int NT = K >> 6;

    const unsigned short* srcA[4];
    const unsigned short* srcB[4];
    #pragma unroll
    for (int i = 0; i < 4; ++i) {
        const int ch = i * 256 + tid;
        const int row = ch >> 3, sl = ch & 7;
        const int scol = (sl ^ (row & 7)) << 3;
        srcA[i] = A + (size_t)(bm0 + row) * K + scol;
        srcB[i] = W + (size_t)(bn0 + row) * K + scol;
    }

    f32x4 acc[4][4] = {};

    #pragma unroll
    for (int i = 0; i < 4; ++i) {
        const int ch = i * 256 + tid;
        GLL16(srcA[i], &aL[0][ch * 8]);
        GLL16(srcB[i], &bL[0][ch * 8]);
    }
    __syncthreads();

    for (int t = 0; t < NT; ++t) {
        const int cur = t & 1, nxt = cur ^ 1;
        if (t + 1 < NT) {
            const int kt1 = (t + 1) << 6;
            #pragma unroll
            for (int i = 0; i < 4; ++i) {
                const int ch = i * 256 + tid;
                GLL16(srcA[i] + kt1, &aL[nxt][ch * 8]);
                GLL16(srcB[i] + kt1, &bL[nxt][ch * 8]);
            }
        }
        bf16x8 av[4][2], bv[4][2];
        #pragma unroll
        for (int ni = 0; ni < 4; ++ni)
            #pragma unroll
            for (int kk = 0; kk < 2; ++kk) {
                const int row = wn * 64 + ni * 16 + l15;
                const int sl = (kk * 4 + l4) ^ (row & 7);
                bv[ni][kk] = *(const bf16x8*)&bL[cur][row * 64 + sl * 8];
            }
        #pragma unroll
        for (int mi = 0; mi < 4; ++mi)
            #pragma unroll
            for (int kk = 0; kk < 2; ++kk) {
                const int row = wm * 64 + mi * 16 + l15;
                const int sl = (kk * 4 + l4) ^ (row & 7);
                av[mi][kk] = *(const bf16x8*)&aL[cur][row * 64 + sl * 8];
            }
        #pragma unroll
        for (int mi = 0; mi < 4; ++mi)
            #pragma unroll
            for (int ni = 0; ni < 4; ++ni)
                #pragma unroll
                for (int kk = 0; kk < 2; ++kk)
                    acc[mi][ni] = __builtin_amdgcn_mfma_f32_16x16x32_bf16(
                        av[mi][kk], bv[ni][kk], acc[mi][ni], 0, 0, 0);
        __syncthreads();
    }

    #pragma unroll
    for (int mi = 0; mi < 4; ++mi) {
        #pragma unroll
        for (int ni = 0; ni < 4; ++ni) {
            const int col = bn0 + wn * 64 + ni * 16 + l15;
            const float bvl = bias[col];
            #pragma unroll
            for (int j = 0; j < 4; ++j) {
                const int r = bm0 + wm * 64 + mi * 16 + l4 * 4 + j;
                float v = acc[mi][ni][j] + bvl;
                if (GELU) v = 0.5f * v * (1.0f + erff(v * 0.70710678118f));
                const size_t idx = (size_t)r * N + col;
                if (RES) ((float*)out)[idx] = res[idx] + v;
                else     ((unsigned short*)out)[idx] = f2bf(v);
            }
        }
    }
}

// ---------------------------------------------------------------------------
// Flash attention (non-causal). KVBLK=64: LDS 24KB -> ~5 blocks/CU.
// Swizzles (8-slot rows): kL slot^=key&7 (pre-swizzled global source);
// vT [d][64] slot^=d&7 (write = one d x 64 keys, 128B-dense);
// pL [q][64] slot^=q&7. All write/read pairs matched involutions.
// ---------------------------------------------------------------------------
__global__ __launch_bounds__(256, 2)
void attn_kernel(const unsigned short* __restrict__ qkv,
                 unsigned short* __restrict__ y) {
    __shared__ unsigned short kL[64 * 64];    // [key][d] swizzled
    __shared__ unsigned short vT[64 * 64];    // [d][key] swizzled
    __shared__ unsigned short pL[4][16 * 64]; // per-wave P [qrow][key] swizzled
    const int tid  = threadIdx.x;
    const int lane = tid & 63;
    const int wave = tid >> 6;
    const int l15 = lane & 15, l4 = lane >> 4;
    const int bh = blockIdx.y, b = bh >> 4, h = bh & 15;
    const int q0 = blockIdx.x * 64;
    const size_t base = (size_t)b * Tn * (3 * Cn);

    const int tq = q0 + wave * 16 + l15;
    const unsigned short* qp = qkv + base + (size_t)tq * (3 * Cn) + h * Dn;
    const bf16x8 qf0 = *(const bf16x8*)(qp + l4 * 8);
    const bf16x8 qf1 = *(const bf16x8*)(qp + 32 + l4 * 8);

    float mr[4], lr[4];
    f32x4 o[4] = {};
    #pragma unroll
    for (int j = 0; j < 4; ++j) { mr[j] = -1e30f; lr[j] = 0.0f; }

    for (int kt = 0; kt < Tn; kt += 64) {
        // stage K tile [64][64]: LDS linear dest, swizzled GLOBAL source.
        #pragma unroll
        for (int i = 0; i < 2; ++i) {
            const int ch = i * 256 + tid;       // 0..511 (16B chunks)
            const int key = ch >> 3, cs = ch & 7;
            const int c_log = cs ^ (key & 7);
            GLL16(qkv + base + (size_t)(kt + key) * (3 * Cn) + Cn + h * Dn + c_log * 8,
                  &kL[ch * 8]);
        }
        // stage V transposed: per (wave,iter) one d-value x 64 keys.
        #pragma unroll
        for (int i = 0; i < 2; ++i) {
            const int ch = i * 256 + tid;
            const int key = ch & 63, c = ch >> 6;   // c in 0..7
            const u16x8 vv = *(const u16x8*)(qkv + base + (size_t)(kt + key) * (3 * Cn)
                                             + 2 * Cn + h * Dn + c * 8);
            #pragma unroll
            for (int j = 0; j < 8; ++j) {
                const int d = c * 8 + j;
                const int ps = ((key >> 3) ^ (d & 7)) * 8 + (key & 7);
                vT[d * 64 + ps] = vv[j];
            }
        }
        __syncthreads();

        // S = (Q K^T) * scale: 16 q-rows x 64 keys per wave
        f32x4 s[4];
        __builtin_amdgcn_s_setprio(1);
        #pragma unroll
        for (int ni = 0; ni < 4; ++ni) {
            const int krow = ni * 16 + l15;
            const int ks = (krow & 7) << 3;
            const bf16x8 kb0 = *(const bf16x8*)&kL[krow * 64 + ((l4 * 8) ^ ks)];
            const bf16x8 kb1 = *(const bf16x8*)&kL[krow * 64 + ((32 + l4 * 8) ^ ks)];
            f32x4 a = {};
            a = __builtin_amdgcn_mfma_f32_16x16x32_bf16(qf0, kb0, a, 0, 0, 0);
            a = __builtin_amdgcn_mfma_f32_16x16x32_bf16(qf1, kb1, a, 0, 0, 0);
            s[ni] = a * 0.125f;
        }
        __builtin_amdgcn_s_setprio(0);

        // online softmax per row (rows live in 16-lane groups)
        #pragma unroll
        for (int j = 0; j < 4; ++j) {
            float tm = -1e30f;
            #pragma unroll
            for (int ni = 0; ni < 4; ++ni) tm = fmaxf(tm, s[ni][j]);
            #pragma unroll
            for (int m = 1; m < 16; m <<= 1) tm = fmaxf(tm, __shfl_xor(tm, m, 64));
            const float mn = fmaxf(mr[j], tm);
            const float al = __expf(mr[j] - mn);
            mr[j] = mn;
            float rs = 0.0f;
            #pragma unroll
            for (int ni = 0; ni < 4; ++ni) {
                const float p = __expf(s[ni][j] - mn);
                s[ni][j] = p;
                rs += p;
            }
            #pragma unroll
            for (int m = 1; m < 16; m <<= 1) rs += __shfl_xor(rs, m, 64);
            lr[j] = lr[j] * al + rs;
            #pragma unroll
            for (int di = 0; di < 4; ++di) o[di][j] *= al;
            const int row = l4 * 4 + j;
            #pragma unroll
            for (int ni = 0; ni < 4; ++ni) {
                const int col = ni * 16 + l15;
                const int ps = (((col >> 3) ^ (row & 7)) << 3) | (col & 7);
                pL[wave][row * 64 + ps] = f2bf(s[ni][j]);
            }
        }

        // O += P V
        __builtin_amdgcn_s_setprio(1);
        #pragma unroll
        for (int kk = 0; kk < 2; ++kk) {
            const int pslot = (kk * 4 + l4) ^ (l15 & 7);
            const bf16x8 pa = *(const bf16x8*)&pL[wave][l15 * 64 + pslot * 8];
            #pragma unroll
            for (int di = 0; di < 4; ++di) {
                const int drow = di * 16 + l15;
                const int vslot = (kk * 4 + l4) ^ (drow & 7);
                const bf16x8 vb = *(const bf16x8*)&vT[drow * 64 + vslot * 8];
                o[di] = __builtin_amdgcn_mfma_f32_16x16x32_bf16(pa, vb, o[di], 0, 0, 0);
            }
        }
        __builtin_amdgcn_s_setprio(0);
        __syncthreads();
    }

    #pragma unroll
    for (int di = 0; di < 4; ++di) {
        #pragma unroll
        for (int j = 0; j < 4; ++j) {
            const int t = q0 + wave * 16 + l4 * 4 + j;
            y[(size_t)(b * Tn + t) * Cn + h * Dn + di * 16 + l15] = f2bf(o[di][j] / lr[j]);
        }
    }
}

// ---------------------------------------------------------------------------
extern "C" void kernel_launch(void* const* d_in, const int* in_sizes, int n_in,
                              void* d_out, int out_size, void* d_ws, size_t ws_size,
                              hipStream_t stream) {
    (void)in_sizes; (void)n_in; (void)out_size; (void)ws_size;
    const float* x      = (const float*)d_in[0];
    const float* ln1_g  = (const float*)d_in[1];
    const float* ln1_b  = (const float*)d_in[2];
    const float* ln2_g  = (const float*)d_in[3];
    const float* ln2_b  = (const float*)d_in[4];
    const float* qkv_w  = (const float*)d_in[5];
    const float* qkv_b  = (const float*)d_in[6];
    const float* proj_w = (const float*)d_in[7];
    const float* proj_b = (const float*)d_in[8];
    const float* fc1_w  = (const float*)d_in[9];
    const float* fc1_b  = (const float*)d_in[10];
    const float* fc2_w  = (const float*)d_in[11];
    const float* fc2_b  = (const float*)d_in[12];

    char* ws = (char*)d_ws;
    unsigned short* wq  = (unsigned short*)(ws + 0);          //  0..6 MB
    unsigned short* wp  = (unsigned short*)(ws + 6291456);    //  6..8 MB
    unsigned short* wf1 = (unsigned short*)(ws + 8388608);    //  8..16 MB
    unsigned short* wf2 = (unsigned short*)(ws + 16777216);   // 16..24 MB
    unsigned short* h   = (unsigned short*)(ws + 25165824);   // 24..40 MB
    unsigned short* qkv = (unsigned short*)(ws + 41943040);   // 40..88 MB
    unsigned short* yb  = (unsigned short*)(ws + 92274688);   // 88..104 MB
    unsigned short* act = (unsigned short*)(ws + 41943040);   // 40..104 MB (over qkv+yb)
    float*          x2  = (float*)d_out;                      // residual stream in d_out

    const int BT = Bn * Tn; // 8192

    conv_bf16<<<dim3(3072), dim3(256), 0, stream>>>(qkv_w, wq, 3 * Cn * Cn / 4);
    conv_bf16<<<dim3(1024), dim3(256), 0, stream>>>(proj_w, wp, Cn * Cn / 4);
    conv_bf16<<<dim3(4096), dim3(256), 0, stream>>>(fc1_w, wf1, 4 * Cn * Cn / 4);
    conv_bf16<<<dim3(4096), dim3(256), 0, stream>>>(fc2_w, wf2, 4 * Cn * Cn / 4);

    ln_kernel<<<dim3(BT), dim3(256), 0, stream>>>(x, ln1_g, ln1_b, h);
    gemm_bt<false, false><<<dim3(3 * Cn / 128, BT / 128), dim3(256), 0, stream>>>(
        h, wq, qkv_b, nullptr, qkv, BT, 3 * Cn, Cn);
    attn_kernel<<<dim3(Tn / 64, Bn * Hn), dim3(256), 0, stream>>>(qkv, yb);
    gemm_bt<false, true><<<dim3(Cn / 128, BT / 128), dim3(256), 0, stream>>>(
        yb, wp, proj_b, x, x2, BT, Cn, Cn);
    ln_kernel<<<dim3(BT), dim3(256), 0, stream>>>(x2, ln2_g, ln2_b, h);
    gemm_bt<true, false><<<dim3(4 * Cn / 128, BT / 128), dim3(256), 0, stream>>>(
        h, wf1, fc1_b, nullptr, act, BT, 4 * Cn, Cn);
    gemm_bt<false, true><<<dim3(Cn / 128, BT / 128), dim3(256), 0, stream>>>(
        act, wf2, fc2_b, x2, (float*)d_out, BT, Cn, 4 * Cn);
}